// Round 14
// baseline (210.207 us; speedup 1.0000x reference)
//
#include <hip/hip_runtime.h>
#include <cstdint>

// ---------------------------------------------------------------------------
// EncoderLayer: x -> MHA(flash, KV-split2, swapped-QK^T in-lane softmax,
//               ones-MFMA row-sum, bf16 partials) -> +res,LN -> FFN -> +res,LN
// B=2, S=2048, D=768, H=12, Dk=64, Dff=3072. fp32 in/out, bf16 MFMA internal.
// ---------------------------------------------------------------------------

typedef unsigned short u16;
typedef unsigned int u32;
typedef __attribute__((ext_vector_type(4))) float f32x4;
typedef __attribute__((ext_vector_type(8))) short s16x8;   // 8 bf16 = 4 VGPRs
typedef __attribute__((ext_vector_type(4))) u16  u16x4;
typedef __attribute__((ext_vector_type(2))) u32  u32x2;

#define AS1 __attribute__((address_space(1)))
#define AS3 __attribute__((address_space(3)))

__device__ __forceinline__ u16 f2b(float f) {            // fp32 -> bf16 RNE
  union { float f; unsigned u; } v; v.f = f;
  unsigned r = v.u + 0x7FFFu + ((v.u >> 16) & 1u);
  return (u16)(r >> 16);
}

__device__ __forceinline__ float b2f(u16 v) {
  union { float f; u32 u; } x; x.u = ((u32)v) << 16; return x.f;
}

// async global->LDS, 16B per lane; LDS dest is wave-uniform base + lane*16
__device__ __forceinline__ void gl_lds16(const void* g, void* lds_uniform_base) {
  __builtin_amdgcn_global_load_lds((const AS1 void*)g, (AS3 void*)lds_uniform_base, 16, 0, 0);
}

__device__ __forceinline__ f32x4 mfma16(s16x8 a, s16x8 b, f32x4 c) {
  return __builtin_amdgcn_mfma_f32_16x16x32_bf16(a, b, c, 0, 0, 0);
}

__device__ __forceinline__ u32 cvt_pk_bf16(float lo, float hi) {
  u32 r;
  asm("v_cvt_pk_bf16_f32 %0, %1, %2" : "=v"(r) : "v"(lo), "v"(hi));
  return r;
}

__device__ __forceinline__ float max3f(float a, float b, float c) {
  return fmaxf(fmaxf(a, b), c);                    // clang fuses -> v_max3_f32
}

// raw workgroup barrier with compiler-level memory fence (no vmcnt drain)
__device__ __forceinline__ void block_barrier() {
  asm volatile("" ::: "memory");
  __builtin_amdgcn_s_barrier();
  asm volatile("" ::: "memory");
}

// ---------------------------------------------------------------------------
// prep: ALL weight transposes (fp32->bf16^T) + x->bf16 + bias concat, one launch
// ---------------------------------------------------------------------------
__global__ __launch_bounds__(256) void prep(
    const float* __restrict__ Wq, const float* __restrict__ Wk,
    const float* __restrict__ Wv, const float* __restrict__ Wo,
    const float* __restrict__ W1, const float* __restrict__ W2,
    const float* __restrict__ bq, const float* __restrict__ bk,
    const float* __restrict__ bv, const float* __restrict__ x,
    u16* __restrict__ Wqkv_t, u16* __restrict__ Wo_t,
    u16* __restrict__ W1_t, u16* __restrict__ W2_t,
    float* __restrict__ bqkv, u16* __restrict__ Xb, int convBlocks) {
  __shared__ float ts[32][33];
  const int bid = blockIdx.x;
  const int tx = threadIdx.x, ty = threadIdx.y;    // (32, 8)
  if (bid < 6912) {
    const float* W; u16* Wt; int K, N, tile;
    if (bid < 2304) {
      int w = bid / 576; tile = bid - w * 576; K = 768; N = 768;
      W = (w == 0) ? Wq : (w == 1) ? Wk : (w == 2) ? Wv : Wo;
      Wt = (w < 3) ? Wqkv_t + (size_t)w * 768 * 768 : Wo_t;
    } else if (bid < 4608) {
      tile = bid - 2304; K = 768; N = 3072; W = W1; Wt = W1_t;
    } else {
      tile = bid - 4608; K = 3072; N = 768; W = W2; Wt = W2_t;
    }
    int ntx = N >> 5;
    int n0 = (tile % ntx) * 32, k0 = (tile / ntx) * 32;
#pragma unroll
    for (int yy = 0; yy < 32; yy += 8)
      ts[ty + yy][tx] = W[(size_t)(k0 + ty + yy) * N + n0 + tx];
    __syncthreads();
#pragma unroll
    for (int yy = 0; yy < 32; yy += 8)
      Wt[(size_t)(n0 + ty + yy) * K + k0 + tx] = f2b(ts[tx][ty + yy]);
  } else if (bid < 6912 + convBlocks) {
    int t = ty * 32 + tx;
    size_t i = ((size_t)(bid - 6912) * 256 + t) * 4;
    f32x4 v = *(const f32x4*)(x + i);
    u16x4 o;
#pragma unroll
    for (int k = 0; k < 4; ++k) o[k] = f2b(v[k]);
    *(u16x4*)(Xb + i) = o;
  } else {
    int t = ty * 32 + tx;
    int i = (bid - 6912 - convBlocks) * 256 + t;
    if (i < 2304) bqkv[i] = (i < 768) ? bq[i] : (i < 1536) ? bk[i - 768] : bv[i - 1536];
  }
}

// ---------------------------------------------------------------------------
// GEMM v3 (round-12/13 proven): 128x128 tile, T2 both-sides swizzle, split-K,
// XCD-chunked remap, counted-vmcnt double-buffered staging.
// MODE 0: bf16 partial out (bias only in chunk 0)
// MODE 1: relu -> bf16 out
// MODE 2: QKV head-split; Q pre-scaled 0.125*log2(e); V written transposed.
// ---------------------------------------------------------------------------
template <int MODE>
__global__ __launch_bounds__(256) void gemm_bt(const u16* __restrict__ A,
                                               const u16* __restrict__ Bt,
                                               const float* __restrict__ bias,
                                               u16* __restrict__ Cb,
                                               u16* __restrict__ Qo, u16* __restrict__ Ko,
                                               u16* __restrict__ Vt, int M, int N, int K,
                                               int Klen) {
  __shared__ __align__(16) u16 lsA[2][128 * 64];
  __shared__ __align__(16) u16 lsB[2][128 * 64];
  const int tid = threadIdx.x;
  const int lane = tid & 63, wave = tid >> 6;
  const int lr = lane & 15, lh = lane >> 4;
  const int wr = wave >> 1, wc = wave & 1;

  int bx, by, bz;
  {
    int nx = gridDim.x, ny = gridDim.y, nz = gridDim.z;
    int total = nx * ny * nz;
    int lin = blockIdx.x + nx * (blockIdx.y + ny * blockIdx.z);
    if ((total & 7) == 0) {
      int key = (lin & 7) * (total >> 3) + (lin >> 3);
      by = key % ny;
      int t2 = key / ny;
      bz = t2 % nz;
      bx = t2 / nz;
    } else {
      bx = blockIdx.x; by = blockIdx.y; bz = blockIdx.z;
    }
  }
  const int m0 = by * 128;
  const int n0 = bx * 128;
  const int kB = bz * Klen;

  f32x4 acc[4][4];
#pragma unroll
  for (int i = 0; i < 4; ++i)
#pragma unroll
    for (int j = 0; j < 4; ++j) acc[i][j] = f32x4{0.f, 0.f, 0.f, 0.f};

  const size_t aBase = (size_t)m0 * K;
  const size_t bBase = (size_t)n0 * K;
  const int srow8 = tid >> 3;                      // 0..31
  const int scolE = (((tid & 7) * 16) ^ ((srow8 & 7) << 4)) >> 1;
  const int xk = (lr & 7) << 4;                    // ds_read XOR key

  auto stage = [&](int buf, int kt) {
#pragma unroll
    for (int i = 0; i < 4; ++i) {
      int row = i * 32 + srow8;
      int ldsOff = buf * 16384 + i * 4096 + wave * 1024;
      gl_lds16(A + aBase + (size_t)row * K + kt + scolE, (char*)lsA + ldsOff);
      gl_lds16(Bt + bBase + (size_t)row * K + kt + scolE, (char*)lsB + ldsOff);
    }
  };

  const int nk = Klen >> 6;
  stage(0, kB);
  for (int t = 0; t < nk; ++t) {
    const int cur = t & 1;
    if (t + 1 < nk) {
      stage(cur ^ 1, kB + (t + 1) * 64);           // 8 loads stay in flight
      asm volatile("s_waitcnt vmcnt(8)" ::: "memory");  // cur's loads landed
    } else {
      asm volatile("s_waitcnt vmcnt(0)" ::: "memory");
    }
    block_barrier();                               // cur published block-wide
    const char* baA = (const char*)lsA + cur * 16384;
    const char* baB = (const char*)lsB + cur * 16384;
#pragma unroll
    for (int ks = 0; ks < 2; ++ks) {
      int cb = (ks * 64 + lh * 16) ^ xk;
      s16x8 a[4], b[4];
#pragma unroll
      for (int i = 0; i < 4; ++i) {
        a[i] = *(const s16x8*)(baA + (wr * 64 + i * 16 + lr) * 128 + cb);
        b[i] = *(const s16x8*)(baB + (wc * 64 + i * 16 + lr) * 128 + cb);
      }
#pragma unroll
      for (int i = 0; i < 4; ++i)
#pragma unroll
        for (int j = 0; j < 4; ++j) acc[i][j] = mfma16(a[i], b[j], acc[i][j]);
    }
    block_barrier();                               // cur free for overwrite
  }

  u16* CbP = Cb + (size_t)bz * M * N;              // bf16 partial slot (MODE 0)
#pragma unroll
  for (int i = 0; i < 4; ++i) {
    int growb = m0 + wr * 64 + i * 16 + lh * 4;
#pragma unroll
    for (int j = 0; j < 4; ++j) {
      int col = n0 + wc * 64 + j * 16 + lr;
      float bv = (MODE != 0 || bz == 0) ? bias[col] : 0.f;
      if (MODE == 2) {
        int sel = col / 768;
        int c2 = col - sel * 768;
        int h = c2 >> 6, d = c2 & 63;
        int b = growb >> 11, s0 = growb & 2047;
        if (sel == 2) {
          u16x4 ob;
#pragma unroll
          for (int q = 0; q < 4; ++q) ob[q] = f2b(acc[i][j][q] + bv);
          *(u16x4*)(Vt + (((size_t)(b * 12 + h)) * 64 + d) * 2048 + s0) = ob;
        } else {
#pragma unroll
          for (int q = 0; q < 4; ++q) {
            float v = acc[i][j][q] + bv;
            size_t idx = (((size_t)(b * 12 + h)) * 2048 + (s0 + q)) * 64 + d;
            float vv = (sel == 0) ? v * 0.1803368801f : v;
            u16* dst = (sel == 0) ? Qo : Ko;
            dst[idx] = f2b(vv);
          }
        }
      } else {
#pragma unroll
        for (int q = 0; q < 4; ++q) {
          int grow = growb + q;
          float v = acc[i][j][q] + bv;
          if (MODE == 0) {
            CbP[(size_t)grow * N + col] = f2b(v);
          } else {
            Cb[(size_t)grow * N + col] = f2b(fmaxf(v, 0.f));
          }
        }
      }
    }
  }
}

// ---------------------------------------------------------------------------
// Flash attention v9: = v7 structure with REG-STAGED single-buffered K/V
// (T14): each thread stages one 16B chunk of K and V to registers at tile
// start (latency hides under compute), ds_write after the read-done barrier.
// LDS 48KB -> 32KB -> 4 blocks/CU (32 waves/CU, HW max). Softmax subtract
// folded into the MFMA C-input (st init = -mrow; mrow starts at 0;
// no-rescale path has zero subs). Defer-max THR=11 (log2), ones-MFMA
// row-sum, cvt_pk P, XCD-chunked remap, bf16 partials.
// ---------------------------------------------------------------------------
__global__ __launch_bounds__(512) void attn(const u16* __restrict__ Qh,
                                            const u16* __restrict__ Kh,
                                            const u16* __restrict__ Vt,
                                            u16* __restrict__ Opb,
                                            float* __restrict__ ml,
                                            int nbh, int ntile) {
  __shared__ __align__(16) u16 lsK[64 * 64];      // 8KB [key][dim]  swizzled
  __shared__ __align__(16) u16 lsV[64 * 64];      // 8KB [dim][key]  swizzled
  __shared__ __align__(16) u16 lsP[8][16 * 64];   // 16KB per-wave   swizzled
  const int tid = threadIdx.x, lane = tid & 63, wave = tid >> 6;
  const int lr = lane & 15, lh = lane >> 4;

  int bx = blockIdx.x, bh = blockIdx.y, z = blockIdx.z;
  {
    int nz = gridDim.z;
    int total = 16 * nbh * nz;
    if ((total & 7) == 0) {
      int lin = bx + 16 * (bh + nbh * z);
      int nl = (lin & 7) * (total >> 3) + (lin >> 3);
      bx = nl & 15;
      bh = (nl >> 4) % nbh;
      z = nl / (16 * nbh);
    }
  }
  const int q0 = bx * 128 + wave * 16;
  const size_t kvBase = (size_t)bh * 2048 * 64;
  const int tB = z * ntile;

  const int srow = tid >> 3;                       // 0..63
  const int scol = (((tid & 7) * 16) ^ ((srow & 7) << 4)) >> 1;  // elem offset
  const u16* kSrcBase = Kh + kvBase + (size_t)srow * 64 + scol;
  const u16* vSrcBase = Vt + kvBase + (size_t)srow * 2048 + scol;

  s16x8 qf[2];
#pragma unroll
  for (int ks = 0; ks < 2; ++ks)
    qf[ks] = *(const s16x8*)(Qh + kvBase + (size_t)(q0 + lr) * 64 + ks * 32 + lh * 8);

  s16x8 onesf;
#pragma unroll
  for (int k = 0; k < 8; ++k) onesf[k] = (short)0x3F80;   // bf16 1.0

  f32x4 oacc[4];
  f32x4 aOnes = f32x4{0.f, 0.f, 0.f, 0.f};        // running row-sum
  float mrow = 0.f;                                // 0-based defer-max baseline
#pragma unroll
  for (int d = 0; d < 4; ++d) oacc[d] = f32x4{0.f, 0.f, 0.f, 0.f};

  // T14 reg staging: one 16B chunk of K and V per thread
  s16x8 kr = *(const s16x8*)(kSrcBase + (size_t)tB * 4096);
  s16x8 vr = *(const s16x8*)(vSrcBase + tB * 64);
  *(s16x8*)((char*)lsK + tid * 16) = kr;
  *(s16x8*)((char*)lsV + tid * 16) = vr;
  __syncthreads();

  for (int it = 0; it < ntile; ++it) {
    const bool more = (it + 1 < ntile);
    if (more) {                                    // issue early, consume late
      int t = tB + it + 1;
      kr = *(const s16x8*)(kSrcBase + (size_t)t * 4096);
      vr = *(const s16x8*)(vSrcBase + t * 64);
    }

    s16x8 kb[2][4];
#pragma unroll
    for (int ks = 0; ks < 2; ++ks)
#pragma unroll
      for (int j = 0; j < 4; ++j) {
        int r = j * 16 + lr;
        kb[ks][j] = *(const s16x8*)((const char*)lsK + r * 128 +
                                    ((ks * 64 + lh * 16) ^ ((r & 7) << 4)));
      }

    // S^T - mrow via MFMA C-input
    const float negm = -mrow;
    f32x4 st[4];
#pragma unroll
    for (int j = 0; j < 4; ++j) st[j] = f32x4{negm, negm, negm, negm};
    __builtin_amdgcn_s_setprio(1);
#pragma unroll
    for (int ks = 0; ks < 2; ++ks)
#pragma unroll
      for (int j = 0; j < 4; ++j) st[j] = mfma16(kb[ks][j], qf[ks], st[j]);
    __builtin_amdgcn_s_setprio(0);

    // in-lane max over 16 keys via v_max3 tree, then 2 shfls across lh
    float mx;
    {
      float t0 = max3f(st[0][0], st[0][1], st[0][2]);
      float t1 = max3f(st[0][3], st[1][0], st[1][1]);
      float t2 = max3f(st[1][2], st[1][3], st[2][0]);
      float t3 = max3f(st[2][1], st[2][2], st[2][3]);
      float t4 = max3f(st[3][0], st[3][1], st[3][2]);
      mx = fmaxf(max3f(t0, t1, t2), max3f(t3, t4, st[3][3]));
      mx = fmaxf(mx, __shfl_xor(mx, 16));
      mx = fmaxf(mx, __shfl_xor(mx, 32));
    }
    // defer-max: rescale only when some row grew > 2^11 above baseline
    const bool resc = __any(mx > 11.f);
    if (resc) {
      float al = exp2f(-mx);
      mrow += mx;
#pragma unroll
      for (int q = 0; q < 4; ++q) aOnes[q] *= al;
#pragma unroll
      for (int d = 0; d < 4; ++d)
#pragma unroll
        for (int q = 0; q < 4; ++q) oacc[d][q] *= al;
    }

    // P -> bf16 pairs -> LDS (no subs on the common path)
    if (resc) {
#pragma unroll
      for (int j = 0; j < 4; ++j) {
        float p0 = exp2f(st[j][0] - mx);
        float p1 = exp2f(st[j][1] - mx);
        float p2 = exp2f(st[j][2] - mx);
        float p3 = exp2f(st[j][3] - mx);
        u32x2 pk;
        pk.x = cvt_pk_bf16(p0, p1);
        pk.y = cvt_pk_bf16(p2, p3);
        *(u32x2*)((char*)lsP[wave] + lr * 128 + ((j * 32 + lh * 8) ^ ((lr & 7) << 4))) = pk;
      }
    } else {
#pragma unroll
      for (int j = 0; j < 4; ++j) {
        float p0 = exp2f(st[j][0]);
        float p1 = exp2f(st[j][1]);
        float p2 = exp2f(st[j][2]);
        float p3 = exp2f(st[j][3]);
        u32x2 pk;
        pk.x = cvt_pk_bf16(p0, p1);
        pk.y = cvt_pk_bf16(p2, p3);
        *(u32x2*)((char*)lsP[wave] + lr * 128 + ((j * 32 + lh * 8) ^ ((lr & 7) << 4))) = pk;
      }
    }

    // O^T += V^T P ; row-sum += ones^T P (same pa fragment, matrix pipe)
    __builtin_amdgcn_s_setprio(1);
#pragma unroll
    for (int ks = 0; ks < 2; ++ks) {
      s16x8 pa = *(const s16x8*)((const char*)lsP[wave] + lr * 128 +
                                 ((ks * 64 + lh * 16) ^ ((lr & 7) << 4)));
      aOnes = mfma16(onesf, pa, aOnes);
#pragma unroll
      for (int d = 0; d < 4; ++d) {
        int r = d * 16 + lr;
        s16x8 vb = *(const s16x8*)((const char*)lsV + r * 128 +
                                   ((ks * 64 + lh * 16) ^ ((r & 7) << 4)));
        oacc[d] = mfma16(vb, pa, oacc[d]);
      }
    }
    __builtin_amdgcn_s_setprio(0);

    __syncthreads();                               // all reads of tile it done
    if (more) {
      *(s16x8*)((char*)lsK + tid * 16) = kr;       // publish tile it+1
      *(s16x8*)((char*)lsV + tid * 16) = vr;
      __syncthreads();
    }
  }

  // epilogue: bf16 unnormalized partial O + (m, l)
  {
    int s = q0 + lr;
    size_t r = ((size_t)z * nbh + bh) * 2048 + s;
#pragma unroll
    for (int d = 0; d < 4; ++d) {
      u32x2 pk;
      pk.x = cvt_pk_bf16(oacc[d][0], oacc[d][1]);
      pk.y = cvt_pk_bf16(oacc[d][2], oacc[d][3]);
      *(u32x2*)(Opb + r * 64 + d * 16 + lh * 4) = pk;
    }
    if (lh == 0) { ml[r * 2] = mrow; ml[r * 2 + 1] = aOnes[0]; }
  }
}

// combine NZ KV-split bf16 partials -> ctx (bf16, [b][s][h*64+d] layout)
template <int NZ>
__global__ __launch_bounds__(256) void attn_combine(const u16* __restrict__ Opb,
                                                    const float* __restrict__ ml,
                                                    u16* __restrict__ ctx, int nbh) {
  size_t i = (size_t)blockIdx.x * 256 + threadIdx.x;   // nbh*2048*16 threads
  int d4 = (int)(i & 15);
  size_t rs = i >> 4;
  size_t zs = (size_t)nbh * 2048;
  float m[NZ], l[NZ];
  float mx = -1e30f;
#pragma unroll
  for (int p = 0; p < NZ; ++p) {
    m[p] = ml[(p * zs + rs) * 2];
    l[p] = ml[(p * zs + rs) * 2 + 1];
    mx = fmaxf(mx, m[p]);
  }
  float wsum = 0.f, a[NZ];
#pragma unroll
  for (int p = 0; p < NZ; ++p) { a[p] = exp2f(m[p] - mx); wsum += l[p] * a[p]; }
  float inv = 1.f / wsum;
  f32x4 o = f32x4{0.f, 0.f, 0.f, 0.f};
#pragma unroll
  for (int p = 0; p < NZ; ++p) {
    u16x4 op = *(const u16x4*)(Opb + (p * zs + rs) * 64 + d4 * 4);
#pragma unroll
    for (int k = 0; k < 4; ++k) o[k] += b2f(op[k]) * a[p];
  }
  int bh = (int)(rs >> 11), s = (int)(rs & 2047);
  int b = bh / 12, h = bh - b * 12;
  u16x4 r;
#pragma unroll
  for (int k = 0; k < 4; ++k) r[k] = f2b(o[k] * inv);
  *(u16x4*)(ctx + ((size_t)(b * 2048 + s)) * 768 + h * 64 + d4 * 4) = r;
}

// ---------------------------------------------------------------------------
// residual + LayerNorm over 768 (f32x4 vectorized: lanes 0..191 hold 4 cols);
// yin = sum of NP bf16 partials (split-K GEMM out)
// ---------------------------------------------------------------------------
template <int NP>
__global__ __launch_bounds__(256) void resid_ln(const float* __restrict__ xin,
                                                const u16* __restrict__ yp,
                                                size_t pstride,
                                                const float* __restrict__ gamma,
                                                const float* __restrict__ beta,
                                                float* __restrict__ outf,
                                                u16* __restrict__ outb) {
  const int row = blockIdx.x, t = threadIdx.x;
  const size_t base4 = (size_t)row * 192;          // row offset in f32x4 units
  const bool act = t < 192;
  f32x4 v = f32x4{0.f, 0.f, 0.f, 0.f};
  float s = 0.f, s2 = 0.f;
  if (act) {
    v = ((const f32x4*)xin)[base4 + t];
#pragma unroll
    for (int p = 0; p < NP; ++p) {
      u16x4 y = *(const u16x4*)(yp + p * pstride + (size_t)row * 768 + t * 4);
#pragma unroll
      for (int k = 0; k < 4; ++k) v[k] += b2f(y[k]);
    }
    s = (v[0] + v[1]) + (v[2] + v[3]);
    s2 = (v[0] * v[0] + v[1] * v[1]) + (v[2] * v[2] + v[3] * v[3]);
  }
#pragma unroll
  for (int off = 32; off > 0; off >>= 1) {
    s += __shfl_down(s, off, 64);
    s2 += __shfl_down(s2, off, 64);
  }
  __shared__ float red[8];
  int lane = t & 63, wave = t >> 6;
  if (lane == 0) { red[wave] = s; red[4 + wave] = s2; }
  __syncthreads();
  s = red[0] + red[1] + red[2] + red[3];
  s2 = red[4] + red[5] + red[6] + red[7];
  const float inv = 1.f / 768.f;
  float mu = s * inv;
  float var = fmaxf(s2 * inv - mu * mu, 0.f);
  float rs = rsqrtf(var + 1e-5f);
  if (act) {
    f32x4 g = ((const f32x4*)gamma)[t];
    f32x4 bb = ((const f32x4*)beta)[t];
    f32x4 o;
#pragma unroll
    for (int k = 0; k < 4; ++k) o[k] = (v[k] - mu) * rs * g[k] + bb[k];
    if (outf) ((f32x4*)outf)[base4 + t] = o;
    if (outb) {
      u16x4 ob;
#pragma unroll
      for (int k = 0; k < 4; ++k) ob[k] = f2b(o[k]);
      ((u16x4*)outb)[base4 + t] = ob;
    }
  }
}

// ---------------------------------------------------------------------------
extern "C" void kernel_launch(void* const* d_in, const int* in_sizes, int n_in,
                              void* d_out, int out_size, void* d_ws, size_t ws_size,
                              hipStream_t stream) {
  const float* x   = (const float*)d_in[0];
  const float* Wq  = (const float*)d_in[1];
  const float* bq  = (const float*)d_in[2];
  const float* Wk  = (const float*)d_in[3];
  const float* bk  = (const float*)d_in[4];
  const float* Wv  = (const float*)d_in[5];
  const float* bv  = (const float*)d_in[6];
  const float* Wo  = (const float*)d_in[7];
  const float* bo  = (const float*)d_in[8];
  const float* W1  = (const float*)d_in[9];
  const float* b1  = (const float*)d_in[10];
  const float* W2  = (const float*)d_in[11];
  const float* b2  = (const float*)d_in[12];
  const float* g1  = (const float*)d_in[13];
  const float* be1 = (const float*)d_in[14];
  const float* g2  = (const float*)d_in[15];
  const float* be2 = (const float*)d_in[16];
  float* out = (float*)d_out;

  const int M = in_sizes[0] / 768;   // 4096 tokens
  const int B = M / 2048;            // 2
  const int nbh = B * 12;

  char* ws = (char*)d_ws;
  size_t off = 0;
  auto alloc = [&](size_t bytes) -> void* {
    void* p = ws + off;
    off += (bytes + 255) & ~(size_t)255;
    return p;
  };
  u16*   Wqkv_t = (u16*)alloc((size_t)2304 * 768 * 2);
  u16*   Wo_t   = (u16*)alloc((size_t)768 * 768 * 2);
  u16*   W1_t   = (u16*)alloc((size_t)3072 * 768 * 2);
  u16*   W2_t   = (u16*)alloc((size_t)768 * 3072 * 2);
  float* bqkv   = (float*)alloc(2304 * 4);
  u16*   Xb     = (u16*)alloc((size_t)M * 768 * 2);      // reused as ctx
  u16*   Qh     = (u16*)alloc((size_t)M * 768 * 2);
  u16*   Kh     = (u16*)alloc((size_t)M * 768 * 2);
  u16*   Vt     = (u16*)alloc((size_t)M * 768 * 2);      // V^T, written by QKV GEMM

  size_t pstride = (size_t)M * 768;                      // elems per partial
  size_t fixedRest = pstride * 4 /*x1f*/ + pstride * 2 /*x1b*/ +
                     (size_t)M * 3072 * 2 /*hb*/ + 4096;
  const int ZSPLIT = 2;
  size_t opElems = (size_t)ZSPLIT * nbh * 2048 * 64;     // bf16
  size_t attnBytes = opElems * 2 + (size_t)ZSPLIT * nbh * 2048 * 2 * 4;
  size_t reg4 = attnBytes;
  if (reg4 < pstride * 2 * 4) reg4 = pstride * 2 * 4;    // 4 bf16 partials
  int FSPLIT;
  size_t regionBytes;
  if (off + reg4 + fixedRest <= ws_size) {
    FSPLIT = 4; regionBytes = reg4;
  } else {
    FSPLIT = 2;
    regionBytes = attnBytes > pstride * 2 * 2 ? attnBytes : pstride * 2 * 2;
  }
  float* region = (float*)alloc(regionBytes);
  u16*   Opb  = (u16*)region;
  float* ml   = (float*)((char*)region + opElems * 2);
  u16*   projPart = (u16*)region;              // alive after attn_combine
  u16*   ffnPart  = (u16*)region;              // alive after resid_ln<1st>
  float* x1f  = (float*)alloc(pstride * 4);
  u16*   x1b  = (u16*)alloc(pstride * 2);
  u16*   hb   = (u16*)alloc((size_t)M * 3072 * 2);
  u16*   ctx  = Xb;

  dim3 tb(32, 8);
  const int convBlocks = (M * 768) / 1024;
  prep<<<6912 + convBlocks + 9, tb, 0, stream>>>(
      Wq, Wk, Wv, Wo, W1, W2, bq, bk, bv, x,
      Wqkv_t, Wo_t, W1_t, W2_t, bqkv, Xb, convBlocks);

  // QKV projection; V written directly in transposed [bh][d][S] layout
  gemm_bt<2><<<dim3(2304 / 128, M / 128), 256, 0, stream>>>(
      Xb, Wqkv_t, bqkv, nullptr, Qh, Kh, Vt, M, 2304, 768, 768);

  attn<<<dim3(16, nbh, ZSPLIT), 512, 0, stream>>>(Qh, Kh, Vt, Opb, ml, nbh, 32 / ZSPLIT);
  attn_combine<2><<<nbh * 128, 256, 0, stream>>>(Opb, ml, ctx, nbh);

  // output projection, split-K x2 -> bf16 partials in region
  gemm_bt<0><<<dim3(768 / 128, M / 128, 2), 256, 0, stream>>>(
      ctx, Wo_t, bo, projPart, nullptr, nullptr, nullptr, M, 768, 768, 384);

  resid_ln<2><<<M, 256, 0, stream>>>(x, projPart, pstride, g1, be1, x1f, x1b);

  gemm_bt<1><<<dim3(3072 / 128, M / 128), 256, 0, stream>>>(
      x1b, W1_t, b1, hb, nullptr, nullptr, nullptr, M, 3072, 768, 768);

  if (FSPLIT == 4) {
    gemm_bt<0><<<dim3(768 / 128, M / 128, 4), 256, 0, stream>>>(
        hb, W2_t, b2, ffnPart, nullptr, nullptr, nullptr, M, 768, 3072, 768);
    resid_ln<4><<<M, 256, 0, stream>>>(x1f, ffnPart, pstride, g2, be2, out, nullptr);
  } else {
    gemm_bt<0><<<dim3(768 / 128, M / 128, 2), 256, 0, stream>>>(
        hb, W2_t, b2, ffnPart, nullptr, nullptr, nullptr, M, 768, 3072, 1536);
    resid_ln<2><<<M, 256, 0, stream>>>(x1f, ffnPart, pstride, g2, be2, out, nullptr);
  }
}

// Round 15
// 202.766 us; speedup vs baseline: 1.0367x; 1.0367x over previous
//
#include <hip/hip_runtime.h>
#include <cstdint>

// ---------------------------------------------------------------------------
// EncoderLayer: x -> MHA(flash, KV-split2, swapped-QK^T in-lane softmax,
//               ones-MFMA row-sum, bf16 partials) -> +res,LN -> FFN -> +res,LN
// B=2, S=2048, D=768, H=12, Dk=64, Dff=3072. fp32 in/out, bf16 MFMA internal.
// Round 15: revert attn to the round-13 proven version (dbuf global_load_lds,
// 48KB LDS); all staging perturbations (r6/r7/r10/r14) were neutral-or-worse.
// ---------------------------------------------------------------------------

typedef unsigned short u16;
typedef unsigned int u32;
typedef __attribute__((ext_vector_type(4))) float f32x4;
typedef __attribute__((ext_vector_type(8))) short s16x8;   // 8 bf16 = 4 VGPRs
typedef __attribute__((ext_vector_type(4))) u16  u16x4;
typedef __attribute__((ext_vector_type(2))) u32  u32x2;

#define AS1 __attribute__((address_space(1)))
#define AS3 __attribute__((address_space(3)))

__device__ __forceinline__ u16 f2b(float f) {            // fp32 -> bf16 RNE
  union { float f; unsigned u; } v; v.f = f;
  unsigned r = v.u + 0x7FFFu + ((v.u >> 16) & 1u);
  return (u16)(r >> 16);
}

__device__ __forceinline__ float b2f(u16 v) {
  union { float f; u32 u; } x; x.u = ((u32)v) << 16; return x.f;
}

// async global->LDS, 16B per lane; LDS dest is wave-uniform base + lane*16
__device__ __forceinline__ void gl_lds16(const void* g, void* lds_uniform_base) {
  __builtin_amdgcn_global_load_lds((const AS1 void*)g, (AS3 void*)lds_uniform_base, 16, 0, 0);
}

__device__ __forceinline__ f32x4 mfma16(s16x8 a, s16x8 b, f32x4 c) {
  return __builtin_amdgcn_mfma_f32_16x16x32_bf16(a, b, c, 0, 0, 0);
}

__device__ __forceinline__ u32 cvt_pk_bf16(float lo, float hi) {
  u32 r;
  asm("v_cvt_pk_bf16_f32 %0, %1, %2" : "=v"(r) : "v"(lo), "v"(hi));
  return r;
}

__device__ __forceinline__ float max3f(float a, float b, float c) {
  return fmaxf(fmaxf(a, b), c);                    // clang fuses -> v_max3_f32
}

// raw workgroup barrier with compiler-level memory fence (no vmcnt drain)
__device__ __forceinline__ void block_barrier() {
  asm volatile("" ::: "memory");
  __builtin_amdgcn_s_barrier();
  asm volatile("" ::: "memory");
}

// ---------------------------------------------------------------------------
// prep: ALL weight transposes (fp32->bf16^T) + x->bf16 + bias concat, one launch
// ---------------------------------------------------------------------------
__global__ __launch_bounds__(256) void prep(
    const float* __restrict__ Wq, const float* __restrict__ Wk,
    const float* __restrict__ Wv, const float* __restrict__ Wo,
    const float* __restrict__ W1, const float* __restrict__ W2,
    const float* __restrict__ bq, const float* __restrict__ bk,
    const float* __restrict__ bv, const float* __restrict__ x,
    u16* __restrict__ Wqkv_t, u16* __restrict__ Wo_t,
    u16* __restrict__ W1_t, u16* __restrict__ W2_t,
    float* __restrict__ bqkv, u16* __restrict__ Xb, int convBlocks) {
  __shared__ float ts[32][33];
  const int bid = blockIdx.x;
  const int tx = threadIdx.x, ty = threadIdx.y;    // (32, 8)
  if (bid < 6912) {
    const float* W; u16* Wt; int K, N, tile;
    if (bid < 2304) {
      int w = bid / 576; tile = bid - w * 576; K = 768; N = 768;
      W = (w == 0) ? Wq : (w == 1) ? Wk : (w == 2) ? Wv : Wo;
      Wt = (w < 3) ? Wqkv_t + (size_t)w * 768 * 768 : Wo_t;
    } else if (bid < 4608) {
      tile = bid - 2304; K = 768; N = 3072; W = W1; Wt = W1_t;
    } else {
      tile = bid - 4608; K = 3072; N = 768; W = W2; Wt = W2_t;
    }
    int ntx = N >> 5;
    int n0 = (tile % ntx) * 32, k0 = (tile / ntx) * 32;
#pragma unroll
    for (int yy = 0; yy < 32; yy += 8)
      ts[ty + yy][tx] = W[(size_t)(k0 + ty + yy) * N + n0 + tx];
    __syncthreads();
#pragma unroll
    for (int yy = 0; yy < 32; yy += 8)
      Wt[(size_t)(n0 + ty + yy) * K + k0 + tx] = f2b(ts[tx][ty + yy]);
  } else if (bid < 6912 + convBlocks) {
    int t = ty * 32 + tx;
    size_t i = ((size_t)(bid - 6912) * 256 + t) * 4;
    f32x4 v = *(const f32x4*)(x + i);
    u16x4 o;
#pragma unroll
    for (int k = 0; k < 4; ++k) o[k] = f2b(v[k]);
    *(u16x4*)(Xb + i) = o;
  } else {
    int t = ty * 32 + tx;
    int i = (bid - 6912 - convBlocks) * 256 + t;
    if (i < 2304) bqkv[i] = (i < 768) ? bq[i] : (i < 1536) ? bk[i - 768] : bv[i - 1536];
  }
}

// ---------------------------------------------------------------------------
// GEMM v3 (round-12/13 proven): 128x128 tile, T2 both-sides swizzle, split-K,
// XCD-chunked remap, counted-vmcnt double-buffered staging.
// MODE 0: bf16 partial out (bias only in chunk 0)
// MODE 1: relu -> bf16 out
// MODE 2: QKV head-split; Q pre-scaled 0.125*log2(e); V written transposed.
// ---------------------------------------------------------------------------
template <int MODE>
__global__ __launch_bounds__(256) void gemm_bt(const u16* __restrict__ A,
                                               const u16* __restrict__ Bt,
                                               const float* __restrict__ bias,
                                               u16* __restrict__ Cb,
                                               u16* __restrict__ Qo, u16* __restrict__ Ko,
                                               u16* __restrict__ Vt, int M, int N, int K,
                                               int Klen) {
  __shared__ __align__(16) u16 lsA[2][128 * 64];
  __shared__ __align__(16) u16 lsB[2][128 * 64];
  const int tid = threadIdx.x;
  const int lane = tid & 63, wave = tid >> 6;
  const int lr = lane & 15, lh = lane >> 4;
  const int wr = wave >> 1, wc = wave & 1;

  int bx, by, bz;
  {
    int nx = gridDim.x, ny = gridDim.y, nz = gridDim.z;
    int total = nx * ny * nz;
    int lin = blockIdx.x + nx * (blockIdx.y + ny * blockIdx.z);
    if ((total & 7) == 0) {
      int key = (lin & 7) * (total >> 3) + (lin >> 3);
      by = key % ny;
      int t2 = key / ny;
      bz = t2 % nz;
      bx = t2 / nz;
    } else {
      bx = blockIdx.x; by = blockIdx.y; bz = blockIdx.z;
    }
  }
  const int m0 = by * 128;
  const int n0 = bx * 128;
  const int kB = bz * Klen;

  f32x4 acc[4][4];
#pragma unroll
  for (int i = 0; i < 4; ++i)
#pragma unroll
    for (int j = 0; j < 4; ++j) acc[i][j] = f32x4{0.f, 0.f, 0.f, 0.f};

  const size_t aBase = (size_t)m0 * K;
  const size_t bBase = (size_t)n0 * K;
  const int srow8 = tid >> 3;                      // 0..31
  const int scolE = (((tid & 7) * 16) ^ ((srow8 & 7) << 4)) >> 1;
  const int xk = (lr & 7) << 4;                    // ds_read XOR key

  auto stage = [&](int buf, int kt) {
#pragma unroll
    for (int i = 0; i < 4; ++i) {
      int row = i * 32 + srow8;
      int ldsOff = buf * 16384 + i * 4096 + wave * 1024;
      gl_lds16(A + aBase + (size_t)row * K + kt + scolE, (char*)lsA + ldsOff);
      gl_lds16(Bt + bBase + (size_t)row * K + kt + scolE, (char*)lsB + ldsOff);
    }
  };

  const int nk = Klen >> 6;
  stage(0, kB);
  for (int t = 0; t < nk; ++t) {
    const int cur = t & 1;
    if (t + 1 < nk) {
      stage(cur ^ 1, kB + (t + 1) * 64);           // 8 loads stay in flight
      asm volatile("s_waitcnt vmcnt(8)" ::: "memory");  // cur's loads landed
    } else {
      asm volatile("s_waitcnt vmcnt(0)" ::: "memory");
    }
    block_barrier();                               // cur published block-wide
    const char* baA = (const char*)lsA + cur * 16384;
    const char* baB = (const char*)lsB + cur * 16384;
#pragma unroll
    for (int ks = 0; ks < 2; ++ks) {
      int cb = (ks * 64 + lh * 16) ^ xk;
      s16x8 a[4], b[4];
#pragma unroll
      for (int i = 0; i < 4; ++i) {
        a[i] = *(const s16x8*)(baA + (wr * 64 + i * 16 + lr) * 128 + cb);
        b[i] = *(const s16x8*)(baB + (wc * 64 + i * 16 + lr) * 128 + cb);
      }
#pragma unroll
      for (int i = 0; i < 4; ++i)
#pragma unroll
        for (int j = 0; j < 4; ++j) acc[i][j] = mfma16(a[i], b[j], acc[i][j]);
    }
    block_barrier();                               // cur free for overwrite
  }

  u16* CbP = Cb + (size_t)bz * M * N;              // bf16 partial slot (MODE 0)
#pragma unroll
  for (int i = 0; i < 4; ++i) {
    int growb = m0 + wr * 64 + i * 16 + lh * 4;
#pragma unroll
    for (int j = 0; j < 4; ++j) {
      int col = n0 + wc * 64 + j * 16 + lr;
      float bv = (MODE != 0 || bz == 0) ? bias[col] : 0.f;
      if (MODE == 2) {
        int sel = col / 768;
        int c2 = col - sel * 768;
        int h = c2 >> 6, d = c2 & 63;
        int b = growb >> 11, s0 = growb & 2047;
        if (sel == 2) {
          u16x4 ob;
#pragma unroll
          for (int q = 0; q < 4; ++q) ob[q] = f2b(acc[i][j][q] + bv);
          *(u16x4*)(Vt + (((size_t)(b * 12 + h)) * 64 + d) * 2048 + s0) = ob;
        } else {
#pragma unroll
          for (int q = 0; q < 4; ++q) {
            float v = acc[i][j][q] + bv;
            size_t idx = (((size_t)(b * 12 + h)) * 2048 + (s0 + q)) * 64 + d;
            float vv = (sel == 0) ? v * 0.1803368801f : v;
            u16* dst = (sel == 0) ? Qo : Ko;
            dst[idx] = f2b(vv);
          }
        }
      } else {
#pragma unroll
        for (int q = 0; q < 4; ++q) {
          int grow = growb + q;
          float v = acc[i][j][q] + bv;
          if (MODE == 0) {
            CbP[(size_t)grow * N + col] = f2b(v);
          } else {
            Cb[(size_t)grow * N + col] = f2b(fmaxf(v, 0.f));
          }
        }
      }
    }
  }
}

// ---------------------------------------------------------------------------
// Flash attention v7 (round-13 proven, restored): KV split-2, swapped-operand
// MFMA, 512 threads = 8 waves x 16 Q-rows, dbuf swizzled K/V via
// global_load_lds, in-lane softmax (v_max3 tree), ones-MFMA row-sum,
// cvt_pk-packed P, defer-max (log2), XCD-chunked remap, bf16 partials.
// ---------------------------------------------------------------------------
__global__ __launch_bounds__(512) void attn(const u16* __restrict__ Qh,
                                            const u16* __restrict__ Kh,
                                            const u16* __restrict__ Vt,
                                            u16* __restrict__ Opb,
                                            float* __restrict__ ml,
                                            int nbh, int ntile) {
  __shared__ __align__(16) u16 lsK[2][64 * 64];   // [buf][key][dim]   swizzled
  __shared__ __align__(16) u16 lsV[2][64 * 64];   // [buf][dim][key]   swizzled
  __shared__ __align__(16) u16 lsP[8][16 * 64];   // per-wave [qrow][key] swizzled
  const int tid = threadIdx.x, lane = tid & 63, wave = tid >> 6;
  const int lr = lane & 15, lh = lane >> 4;

  int bx = blockIdx.x, bh = blockIdx.y, z = blockIdx.z;
  {
    int nz = gridDim.z;
    int total = 16 * nbh * nz;
    if ((total & 7) == 0) {
      int lin = bx + 16 * (bh + nbh * z);
      int nl = (lin & 7) * (total >> 3) + (lin >> 3);
      bx = nl & 15;
      bh = (nl >> 4) % nbh;
      z = nl / (16 * nbh);
    }
  }
  const int q0 = bx * 128 + wave * 16;
  const size_t kvBase = (size_t)bh * 2048 * 64;
  const int tB = z * ntile;

  const int srow = tid >> 3;                       // 0..63
  const int scol = (((tid & 7) * 16) ^ ((srow & 7) << 4)) >> 1;  // elem offset
  const u16* kSrcBase = Kh + kvBase + (size_t)srow * 64 + scol;
  const u16* vSrcBase = Vt + kvBase + (size_t)srow * 2048 + scol;

  s16x8 qf[2];
#pragma unroll
  for (int ks = 0; ks < 2; ++ks)
    qf[ks] = *(const s16x8*)(Qh + kvBase + (size_t)(q0 + lr) * 64 + ks * 32 + lh * 8);

  s16x8 onesf;
#pragma unroll
  for (int k = 0; k < 8; ++k) onesf[k] = (short)0x3F80;   // bf16 1.0

  f32x4 oacc[4];
  f32x4 aOnes = f32x4{0.f, 0.f, 0.f, 0.f};        // running row-sum
  float mrow = -1e30f;
#pragma unroll
  for (int d = 0; d < 4; ++d) oacc[d] = f32x4{0.f, 0.f, 0.f, 0.f};

  gl_lds16(kSrcBase + (size_t)tB * 4096, (char*)lsK[0] + wave * 1024);
  gl_lds16(vSrcBase + tB * 64,           (char*)lsV[0] + wave * 1024);

  for (int it = 0; it < ntile; ++it) {
    const int cur = it & 1;
    __syncthreads();

    s16x8 kb[2][4];
#pragma unroll
    for (int ks = 0; ks < 2; ++ks)
#pragma unroll
      for (int j = 0; j < 4; ++j) {
        int r = j * 16 + lr;
        kb[ks][j] = *(const s16x8*)((const char*)lsK[cur] + r * 128 +
                                    ((ks * 64 + lh * 16) ^ ((r & 7) << 4)));
      }

    if (it + 1 < ntile) {
      int t = tB + it + 1;
      gl_lds16(kSrcBase + (size_t)t * 4096, (char*)lsK[cur ^ 1] + wave * 1024);
      gl_lds16(vSrcBase + t * 64,           (char*)lsV[cur ^ 1] + wave * 1024);
    }

    f32x4 st[4];
#pragma unroll
    for (int j = 0; j < 4; ++j) st[j] = f32x4{0.f, 0.f, 0.f, 0.f};
    __builtin_amdgcn_s_setprio(1);
#pragma unroll
    for (int ks = 0; ks < 2; ++ks)
#pragma unroll
      for (int j = 0; j < 4; ++j) st[j] = mfma16(kb[ks][j], qf[ks], st[j]);
    __builtin_amdgcn_s_setprio(0);

    // in-lane max over 16 keys via v_max3 tree, then 2 shfls across lh
    float mx;
    {
      float t0 = max3f(st[0][0], st[0][1], st[0][2]);
      float t1 = max3f(st[0][3], st[1][0], st[1][1]);
      float t2 = max3f(st[1][2], st[1][3], st[2][0]);
      float t3 = max3f(st[2][1], st[2][2], st[2][3]);
      float t4 = max3f(st[3][0], st[3][1], st[3][2]);
      mx = fmaxf(max3f(t0, t1, t2), max3f(t3, t4, st[3][3]));
      mx = fmaxf(mx, __shfl_xor(mx, 16));
      mx = fmaxf(mx, __shfl_xor(mx, 32));
    }
    // defer-max: rescale only when some row grew > 2^11 (log2 domain)
    if (__any(mx > mrow + 11.f)) {
      float mn = fmaxf(mrow, mx);
      float al = exp2f(mrow - mn);
      mrow = mn;
#pragma unroll
      for (int q = 0; q < 4; ++q) aOnes[q] *= al;
#pragma unroll
      for (int d = 0; d < 4; ++d)
#pragma unroll
        for (int q = 0; q < 4; ++q) oacc[d][q] *= al;
    }

    // P = exp2(S - m) -> bf16 pairs -> LDS (row-sum via ones-MFMA below)
#pragma unroll
    for (int j = 0; j < 4; ++j) {
      float p0 = exp2f(st[j][0] - mrow);
      float p1 = exp2f(st[j][1] - mrow);
      float p2 = exp2f(st[j][2] - mrow);
      float p3 = exp2f(st[j][3] - mrow);
      u32x2 pk;
      pk.x = cvt_pk_bf16(p0, p1);
      pk.y = cvt_pk_bf16(p2, p3);
      *(u32x2*)((char*)lsP[wave] + lr * 128 + ((j * 32 + lh * 8) ^ ((lr & 7) << 4))) = pk;
    }

    // O^T += V^T P ; row-sum += ones^T P (same pa fragment, matrix pipe)
    __builtin_amdgcn_s_setprio(1);
#pragma unroll
    for (int ks = 0; ks < 2; ++ks) {
      s16x8 pa = *(const s16x8*)((const char*)lsP[wave] + lr * 128 +
                                 ((ks * 64 + lh * 16) ^ ((lr & 7) << 4)));
      aOnes = mfma16(onesf, pa, aOnes);
#pragma unroll
      for (int d = 0; d < 4; ++d) {
        int r = d * 16 + lr;
        s16x8 vb = *(const s16x8*)((const char*)lsV[cur] + r * 128 +
                                   ((ks * 64 + lh * 16) ^ ((r & 7) << 4)));
        oacc[d] = mfma16(vb, pa, oacc[d]);
      }
    }
    __builtin_amdgcn_s_setprio(0);
  }

  // epilogue: bf16 unnormalized partial O + (m, l)
  {
    int s = q0 + lr;
    size_t r = ((size_t)z * nbh + bh) * 2048 + s;
#pragma unroll
    for (int d = 0; d < 4; ++d) {
      u32x2 pk;
      pk.x = cvt_pk_bf16(oacc[d][0], oacc[d][1]);
      pk.y = cvt_pk_bf16(oacc[d][2], oacc[d][3]);
      *(u32x2*)(Opb + r * 64 + d * 16 + lh * 4) = pk;
    }
    if (lh == 0) { ml[r * 2] = mrow; ml[r * 2 + 1] = aOnes[0]; }
  }
}

// combine NZ KV-split bf16 partials -> ctx (bf16, [b][s][h*64+d] layout)
template <int NZ>
__global__ __launch_bounds__(256) void attn_combine(const u16* __restrict__ Opb,
                                                    const float* __restrict__ ml,
                                                    u16* __restrict__ ctx, int nbh) {
  size_t i = (size_t)blockIdx.x * 256 + threadIdx.x;   // nbh*2048*16 threads
  int d4 = (int)(i & 15);
  size_t rs = i >> 4;
  size_t zs = (size_t)nbh * 2048;
  float m[NZ], l[NZ];
  float mx = -1e30f;
#pragma unroll
  for (int p = 0; p < NZ; ++p) {
    m[p] = ml[(p * zs + rs) * 2];
    l[p] = ml[(p * zs + rs) * 2 + 1];
    mx = fmaxf(mx, m[p]);
  }
  float wsum = 0.f, a[NZ];
#pragma unroll
  for (int p = 0; p < NZ; ++p) { a[p] = exp2f(m[p] - mx); wsum += l[p] * a[p]; }
  float inv = 1.f / wsum;
  f32x4 o = f32x4{0.f, 0.f, 0.f, 0.f};
#pragma unroll
  for (int p = 0; p < NZ; ++p) {
    u16x4 op = *(const u16x4*)(Opb + (p * zs + rs) * 64 + d4 * 4);
#pragma unroll
    for (int k = 0; k < 4; ++k) o[k] += b2f(op[k]) * a[p];
  }
  int bh = (int)(rs >> 11), s = (int)(rs & 2047);
  int b = bh / 12, h = bh - b * 12;
  u16x4 r;
#pragma unroll
  for (int k = 0; k < 4; ++k) r[k] = f2b(o[k] * inv);
  *(u16x4*)(ctx + ((size_t)(b * 2048 + s)) * 768 + h * 64 + d4 * 4) = r;
}

// ---------------------------------------------------------------------------
// residual + LayerNorm over 768 (f32x4 vectorized: lanes 0..191 hold 4 cols);
// yin = sum of NP bf16 partials (split-K GEMM out)
// ---------------------------------------------------------------------------
template <int NP>
__global__ __launch_bounds__(256) void resid_ln(const float* __restrict__ xin,
                                                const u16* __restrict__ yp,
                                                size_t pstride,
                                                const float* __restrict__ gamma,
                                                const float* __restrict__ beta,
                                                float* __restrict__ outf,
                                                u16* __restrict__ outb) {
  const int row = blockIdx.x, t = threadIdx.x;
  const size_t base4 = (size_t)row * 192;          // row offset in f32x4 units
  const bool act = t < 192;
  f32x4 v = f32x4{0.f, 0.f, 0.f, 0.f};
  float s = 0.f, s2 = 0.f;
  if (act) {
    v = ((const f32x4*)xin)[base4 + t];
#pragma unroll
    for (int p = 0; p < NP; ++p) {
      u16x4 y = *(const u16x4*)(yp + p * pstride + (size_t)row * 768 + t * 4);
#pragma unroll
      for (int k = 0; k < 4; ++k) v[k] += b2f(y[k]);
    }
    s = (v[0] + v[1]) + (v[2] + v[3]);
    s2 = (v[0] * v[0] + v[1] * v[1]) + (v[2] * v[2] + v[3] * v[3]);
  }
#pragma unroll
  for (int off = 32; off > 0; off >>= 1) {
    s += __shfl_down(s, off, 64);
    s2 += __shfl_down(s2, off, 64);
  }
  __shared__ float red[8];
  int lane = t & 63, wave = t >> 6;
  if (lane == 0) { red[wave] = s; red[4 + wave] = s2; }
  __syncthreads();
  s = red[0] + red[1] + red[2] + red[3];
  s2 = red[4] + red[5] + red[6] + red[7];
  const float inv = 1.f / 768.f;
  float mu = s * inv;
  float var = fmaxf(s2 * inv - mu * mu, 0.f);
  float rs = rsqrtf(var + 1e-5f);
  if (act) {
    f32x4 g = ((const f32x4*)gamma)[t];
    f32x4 bb = ((const f32x4*)beta)[t];
    f32x4 o;
#pragma unroll
    for (int k = 0; k < 4; ++k) o[k] = (v[k] - mu) * rs * g[k] + bb[k];
    if (outf) ((f32x4*)outf)[base4 + t] = o;
    if (outb) {
      u16x4 ob;
#pragma unroll
      for (int k = 0; k < 4; ++k) ob[k] = f2b(o[k]);
      ((u16x4*)outb)[base4 + t] = ob;
    }
  }
}

// ---------------------------------------------------------------------------
extern "C" void kernel_launch(void* const* d_in, const int* in_sizes, int n_in,
                              void* d_out, int out_size, void* d_ws, size_t ws_size,
                              hipStream_t stream) {
  const float* x   = (const float*)d_in[0];
  const float* Wq  = (const float*)d_in[1];
  const float* bq  = (const float*)d_in[2];
  const float* Wk  = (const float*)d_in[3];
  const float* bk  = (const float*)d_in[4];
  const float* Wv  = (const float*)d_in[5];
  const float* bv  = (const float*)d_in[6];
  const float* Wo  = (const float*)d_in[7];
  const float* bo  = (const float*)d_in[8];
  const float* W1  = (const float*)d_in[9];
  const float* b1  = (const float*)d_in[10];
  const float* W2  = (const float*)d_in[11];
  const float* b2  = (const float*)d_in[12];
  const float* g1  = (const float*)d_in[13];
  const float* be1 = (const float*)d_in[14];
  const float* g2  = (const float*)d_in[15];
  const float* be2 = (const float*)d_in[16];
  float* out = (float*)d_out;

  const int M = in_sizes[0] / 768;   // 4096 tokens
  const int B = M / 2048;            // 2
  const int nbh = B * 12;

  char* ws = (char*)d_ws;
  size_t off = 0;
  auto alloc = [&](size_t bytes) -> void* {
    void* p = ws + off;
    off += (bytes + 255) & ~(size_t)255;
    return p;
  };
  u16*   Wqkv_t = (u16*)alloc((size_t)2304 * 768 * 2);
  u16*   Wo_t   = (u16*)alloc((size_t)768 * 768 * 2);
  u16*   W1_t   = (u16*)alloc((size_t)3072 * 768 * 2);
  u16*   W2_t   = (u16*)alloc((size_t)768 * 3072 * 2);
  float* bqkv   = (float*)alloc(2304 * 4);
  u16*   Xb     = (u16*)alloc((size_t)M * 768 * 2);      // reused as ctx
  u16*   Qh     = (u16*)alloc((size_t)M * 768 * 2);
  u16*   Kh     = (u16*)alloc((size_t)M * 768 * 2);
  u16*   Vt     = (u16*)alloc((size_t)M * 768 * 2);      // V^T, written by QKV GEMM

  size_t pstride = (size_t)M * 768;                      // elems per partial
  size_t fixedRest = pstride * 4 /*x1f*/ + pstride * 2 /*x1b*/ +
                     (size_t)M * 3072 * 2 /*hb*/ + 4096;
  const int ZSPLIT = 2;
  size_t opElems = (size_t)ZSPLIT * nbh * 2048 * 64;     // bf16
  size_t attnBytes = opElems * 2 + (size_t)ZSPLIT * nbh * 2048 * 2 * 4;
  size_t reg4 = attnBytes;
  if (reg4 < pstride * 2 * 4) reg4 = pstride * 2 * 4;    // 4 bf16 partials
  int FSPLIT;
  size_t regionBytes;
  if (off + reg4 + fixedRest <= ws_size) {
    FSPLIT = 4; regionBytes = reg4;
  } else {
    FSPLIT = 2;
    regionBytes = attnBytes > pstride * 2 * 2 ? attnBytes : pstride * 2 * 2;
  }
  float* region = (float*)alloc(regionBytes);
  u16*   Opb  = (u16*)region;
  float* ml   = (float*)((char*)region + opElems * 2);
  u16*   projPart = (u16*)region;              // alive after attn_combine
  u16*   ffnPart  = (u16*)region;              // alive after resid_ln<1st>
  float* x1f  = (float*)alloc(pstride * 4);
  u16*   x1b  = (u16*)alloc(pstride * 2);
  u16*   hb   = (u16*)alloc((size_t)M * 3072 * 2);
  u16*   ctx  = Xb;

  dim3 tb(32, 8);
  const int convBlocks = (M * 768) / 1024;
  prep<<<6912 + convBlocks + 9, tb, 0, stream>>>(
      Wq, Wk, Wv, Wo, W1, W2, bq, bk, bv, x,
      Wqkv_t, Wo_t, W1_t, W2_t, bqkv, Xb, convBlocks);

  // QKV projection; V written directly in transposed [bh][d][S] layout
  gemm_bt<2><<<dim3(2304 / 128, M / 128), 256, 0, stream>>>(
      Xb, Wqkv_t, bqkv, nullptr, Qh, Kh, Vt, M, 2304, 768, 768);

  attn<<<dim3(16, nbh, ZSPLIT), 512, 0, stream>>>(Qh, Kh, Vt, Opb, ml, nbh, 32 / ZSPLIT);
  attn_combine<2><<<nbh * 128, 256, 0, stream>>>(Opb, ml, ctx, nbh);

  // output projection, split-K x2 -> bf16 partials in region
  gemm_bt<0><<<dim3(768 / 128, M / 128, 2), 256, 0, stream>>>(
      ctx, Wo_t, bo, projPart, nullptr, nullptr, nullptr, M, 768, 768, 384);

  resid_ln<2><<<M, 256, 0, stream>>>(x, projPart, pstride, g1, be1, x1f, x1b);

  gemm_bt<1><<<dim3(3072 / 128, M / 128), 256, 0, stream>>>(
      x1b, W1_t, b1, hb, nullptr, nullptr, nullptr, M, 3072, 768, 768);

  if (FSPLIT == 4) {
    gemm_bt<0><<<dim3(768 / 128, M / 128, 4), 256, 0, stream>>>(
        hb, W2_t, b2, ffnPart, nullptr, nullptr, nullptr, M, 768, 3072, 768);
    resid_ln<4><<<M, 256, 0, stream>>>(x1f, ffnPart, pstride, g2, be2, out, nullptr);
  } else {
    gemm_bt<0><<<dim3(768 / 128, M / 128, 2), 256, 0, stream>>>(
        hb, W2_t, b2, ffnPart, nullptr, nullptr, nullptr, M, 768, 3072, 1536);
    resid_ln<2><<<M, 256, 0, stream>>>(x1f, ffnPart, pstride, g2, be2, out, nullptr);
  }
}

// Round 16
// 200.582 us; speedup vs baseline: 1.0480x; 1.0109x over previous
//
#include <hip/hip_runtime.h>
#include <cstdint>

// ---------------------------------------------------------------------------
// EncoderLayer: x -> MHA(flash, KV-split2, swapped-QK^T in-lane softmax,
//               ones-MFMA row-sum, bf16 partials) -> +res,LN -> FFN -> +res,LN
// B=2, S=2048, D=768, H=12, Dk=64, Dff=3072. fp32 in/out, bf16 MFMA internal.
// Round 16: drop the x1f fp32 residual tensor; LN2 reads the bf16 copy (x1b)
// that FFN1 already consumes. Saves ~25 MB of HBM traffic.
// ---------------------------------------------------------------------------

typedef unsigned short u16;
typedef unsigned int u32;
typedef __attribute__((ext_vector_type(4))) float f32x4;
typedef __attribute__((ext_vector_type(8))) short s16x8;   // 8 bf16 = 4 VGPRs
typedef __attribute__((ext_vector_type(4))) u16  u16x4;
typedef __attribute__((ext_vector_type(2))) u32  u32x2;

#define AS1 __attribute__((address_space(1)))
#define AS3 __attribute__((address_space(3)))

__device__ __forceinline__ u16 f2b(float f) {            // fp32 -> bf16 RNE
  union { float f; unsigned u; } v; v.f = f;
  unsigned r = v.u + 0x7FFFu + ((v.u >> 16) & 1u);
  return (u16)(r >> 16);
}

__device__ __forceinline__ float b2f(u16 v) {
  union { float f; u32 u; } x; x.u = ((u32)v) << 16; return x.f;
}

// async global->LDS, 16B per lane; LDS dest is wave-uniform base + lane*16
__device__ __forceinline__ void gl_lds16(const void* g, void* lds_uniform_base) {
  __builtin_amdgcn_global_load_lds((const AS1 void*)g, (AS3 void*)lds_uniform_base, 16, 0, 0);
}

__device__ __forceinline__ f32x4 mfma16(s16x8 a, s16x8 b, f32x4 c) {
  return __builtin_amdgcn_mfma_f32_16x16x32_bf16(a, b, c, 0, 0, 0);
}

__device__ __forceinline__ u32 cvt_pk_bf16(float lo, float hi) {
  u32 r;
  asm("v_cvt_pk_bf16_f32 %0, %1, %2" : "=v"(r) : "v"(lo), "v"(hi));
  return r;
}

__device__ __forceinline__ float max3f(float a, float b, float c) {
  return fmaxf(fmaxf(a, b), c);                    // clang fuses -> v_max3_f32
}

// raw workgroup barrier with compiler-level memory fence (no vmcnt drain)
__device__ __forceinline__ void block_barrier() {
  asm volatile("" ::: "memory");
  __builtin_amdgcn_s_barrier();
  asm volatile("" ::: "memory");
}

// ---------------------------------------------------------------------------
// prep: ALL weight transposes (fp32->bf16^T) + x->bf16 + bias concat, one launch
// ---------------------------------------------------------------------------
__global__ __launch_bounds__(256) void prep(
    const float* __restrict__ Wq, const float* __restrict__ Wk,
    const float* __restrict__ Wv, const float* __restrict__ Wo,
    const float* __restrict__ W1, const float* __restrict__ W2,
    const float* __restrict__ bq, const float* __restrict__ bk,
    const float* __restrict__ bv, const float* __restrict__ x,
    u16* __restrict__ Wqkv_t, u16* __restrict__ Wo_t,
    u16* __restrict__ W1_t, u16* __restrict__ W2_t,
    float* __restrict__ bqkv, u16* __restrict__ Xb, int convBlocks) {
  __shared__ float ts[32][33];
  const int bid = blockIdx.x;
  const int tx = threadIdx.x, ty = threadIdx.y;    // (32, 8)
  if (bid < 6912) {
    const float* W; u16* Wt; int K, N, tile;
    if (bid < 2304) {
      int w = bid / 576; tile = bid - w * 576; K = 768; N = 768;
      W = (w == 0) ? Wq : (w == 1) ? Wk : (w == 2) ? Wv : Wo;
      Wt = (w < 3) ? Wqkv_t + (size_t)w * 768 * 768 : Wo_t;
    } else if (bid < 4608) {
      tile = bid - 2304; K = 768; N = 3072; W = W1; Wt = W1_t;
    } else {
      tile = bid - 4608; K = 3072; N = 768; W = W2; Wt = W2_t;
    }
    int ntx = N >> 5;
    int n0 = (tile % ntx) * 32, k0 = (tile / ntx) * 32;
#pragma unroll
    for (int yy = 0; yy < 32; yy += 8)
      ts[ty + yy][tx] = W[(size_t)(k0 + ty + yy) * N + n0 + tx];
    __syncthreads();
#pragma unroll
    for (int yy = 0; yy < 32; yy += 8)
      Wt[(size_t)(n0 + ty + yy) * K + k0 + tx] = f2b(ts[tx][ty + yy]);
  } else if (bid < 6912 + convBlocks) {
    int t = ty * 32 + tx;
    size_t i = ((size_t)(bid - 6912) * 256 + t) * 4;
    f32x4 v = *(const f32x4*)(x + i);
    u16x4 o;
#pragma unroll
    for (int k = 0; k < 4; ++k) o[k] = f2b(v[k]);
    *(u16x4*)(Xb + i) = o;
  } else {
    int t = ty * 32 + tx;
    int i = (bid - 6912 - convBlocks) * 256 + t;
    if (i < 2304) bqkv[i] = (i < 768) ? bq[i] : (i < 1536) ? bk[i - 768] : bv[i - 1536];
  }
}

// ---------------------------------------------------------------------------
// GEMM v3 (round-12/13 proven): 128x128 tile, T2 both-sides swizzle, split-K,
// XCD-chunked remap, counted-vmcnt double-buffered staging.
// MODE 0: bf16 partial out (bias only in chunk 0)
// MODE 1: relu -> bf16 out
// MODE 2: QKV head-split; Q pre-scaled 0.125*log2(e); V written transposed.
// ---------------------------------------------------------------------------
template <int MODE>
__global__ __launch_bounds__(256) void gemm_bt(const u16* __restrict__ A,
                                               const u16* __restrict__ Bt,
                                               const float* __restrict__ bias,
                                               u16* __restrict__ Cb,
                                               u16* __restrict__ Qo, u16* __restrict__ Ko,
                                               u16* __restrict__ Vt, int M, int N, int K,
                                               int Klen) {
  __shared__ __align__(16) u16 lsA[2][128 * 64];
  __shared__ __align__(16) u16 lsB[2][128 * 64];
  const int tid = threadIdx.x;
  const int lane = tid & 63, wave = tid >> 6;
  const int lr = lane & 15, lh = lane >> 4;
  const int wr = wave >> 1, wc = wave & 1;

  int bx, by, bz;
  {
    int nx = gridDim.x, ny = gridDim.y, nz = gridDim.z;
    int total = nx * ny * nz;
    int lin = blockIdx.x + nx * (blockIdx.y + ny * blockIdx.z);
    if ((total & 7) == 0) {
      int key = (lin & 7) * (total >> 3) + (lin >> 3);
      by = key % ny;
      int t2 = key / ny;
      bz = t2 % nz;
      bx = t2 / nz;
    } else {
      bx = blockIdx.x; by = blockIdx.y; bz = blockIdx.z;
    }
  }
  const int m0 = by * 128;
  const int n0 = bx * 128;
  const int kB = bz * Klen;

  f32x4 acc[4][4];
#pragma unroll
  for (int i = 0; i < 4; ++i)
#pragma unroll
    for (int j = 0; j < 4; ++j) acc[i][j] = f32x4{0.f, 0.f, 0.f, 0.f};

  const size_t aBase = (size_t)m0 * K;
  const size_t bBase = (size_t)n0 * K;
  const int srow8 = tid >> 3;                      // 0..31
  const int scolE = (((tid & 7) * 16) ^ ((srow8 & 7) << 4)) >> 1;
  const int xk = (lr & 7) << 4;                    // ds_read XOR key

  auto stage = [&](int buf, int kt) {
#pragma unroll
    for (int i = 0; i < 4; ++i) {
      int row = i * 32 + srow8;
      int ldsOff = buf * 16384 + i * 4096 + wave * 1024;
      gl_lds16(A + aBase + (size_t)row * K + kt + scolE, (char*)lsA + ldsOff);
      gl_lds16(Bt + bBase + (size_t)row * K + kt + scolE, (char*)lsB + ldsOff);
    }
  };

  const int nk = Klen >> 6;
  stage(0, kB);
  for (int t = 0; t < nk; ++t) {
    const int cur = t & 1;
    if (t + 1 < nk) {
      stage(cur ^ 1, kB + (t + 1) * 64);           // 8 loads stay in flight
      asm volatile("s_waitcnt vmcnt(8)" ::: "memory");  // cur's loads landed
    } else {
      asm volatile("s_waitcnt vmcnt(0)" ::: "memory");
    }
    block_barrier();                               // cur published block-wide
    const char* baA = (const char*)lsA + cur * 16384;
    const char* baB = (const char*)lsB + cur * 16384;
#pragma unroll
    for (int ks = 0; ks < 2; ++ks) {
      int cb = (ks * 64 + lh * 16) ^ xk;
      s16x8 a[4], b[4];
#pragma unroll
      for (int i = 0; i < 4; ++i) {
        a[i] = *(const s16x8*)(baA + (wr * 64 + i * 16 + lr) * 128 + cb);
        b[i] = *(const s16x8*)(baB + (wc * 64 + i * 16 + lr) * 128 + cb);
      }
#pragma unroll
      for (int i = 0; i < 4; ++i)
#pragma unroll
        for (int j = 0; j < 4; ++j) acc[i][j] = mfma16(a[i], b[j], acc[i][j]);
    }
    block_barrier();                               // cur free for overwrite
  }

  u16* CbP = Cb + (size_t)bz * M * N;              // bf16 partial slot (MODE 0)
#pragma unroll
  for (int i = 0; i < 4; ++i) {
    int growb = m0 + wr * 64 + i * 16 + lh * 4;
#pragma unroll
    for (int j = 0; j < 4; ++j) {
      int col = n0 + wc * 64 + j * 16 + lr;
      float bv = (MODE != 0 || bz == 0) ? bias[col] : 0.f;
      if (MODE == 2) {
        int sel = col / 768;
        int c2 = col - sel * 768;
        int h = c2 >> 6, d = c2 & 63;
        int b = growb >> 11, s0 = growb & 2047;
        if (sel == 2) {
          u16x4 ob;
#pragma unroll
          for (int q = 0; q < 4; ++q) ob[q] = f2b(acc[i][j][q] + bv);
          *(u16x4*)(Vt + (((size_t)(b * 12 + h)) * 64 + d) * 2048 + s0) = ob;
        } else {
#pragma unroll
          for (int q = 0; q < 4; ++q) {
            float v = acc[i][j][q] + bv;
            size_t idx = (((size_t)(b * 12 + h)) * 2048 + (s0 + q)) * 64 + d;
            float vv = (sel == 0) ? v * 0.1803368801f : v;
            u16* dst = (sel == 0) ? Qo : Ko;
            dst[idx] = f2b(vv);
          }
        }
      } else {
#pragma unroll
        for (int q = 0; q < 4; ++q) {
          int grow = growb + q;
          float v = acc[i][j][q] + bv;
          if (MODE == 0) {
            CbP[(size_t)grow * N + col] = f2b(v);
          } else {
            Cb[(size_t)grow * N + col] = f2b(fmaxf(v, 0.f));
          }
        }
      }
    }
  }
}

// ---------------------------------------------------------------------------
// Flash attention v7 (round-13 proven, frozen): KV split-2, swapped-operand
// MFMA, 512 threads = 8 waves x 16 Q-rows, dbuf swizzled K/V via
// global_load_lds, in-lane softmax (v_max3 tree), ones-MFMA row-sum,
// cvt_pk-packed P, defer-max (log2), XCD-chunked remap, bf16 partials.
// ---------------------------------------------------------------------------
__global__ __launch_bounds__(512) void attn(const u16* __restrict__ Qh,
                                            const u16* __restrict__ Kh,
                                            const u16* __restrict__ Vt,
                                            u16* __restrict__ Opb,
                                            float* __restrict__ ml,
                                            int nbh, int ntile) {
  __shared__ __align__(16) u16 lsK[2][64 * 64];   // [buf][key][dim]   swizzled
  __shared__ __align__(16) u16 lsV[2][64 * 64];   // [buf][dim][key]   swizzled
  __shared__ __align__(16) u16 lsP[8][16 * 64];   // per-wave [qrow][key] swizzled
  const int tid = threadIdx.x, lane = tid & 63, wave = tid >> 6;
  const int lr = lane & 15, lh = lane >> 4;

  int bx = blockIdx.x, bh = blockIdx.y, z = blockIdx.z;
  {
    int nz = gridDim.z;
    int total = 16 * nbh * nz;
    if ((total & 7) == 0) {
      int lin = bx + 16 * (bh + nbh * z);
      int nl = (lin & 7) * (total >> 3) + (lin >> 3);
      bx = nl & 15;
      bh = (nl >> 4) % nbh;
      z = nl / (16 * nbh);
    }
  }
  const int q0 = bx * 128 + wave * 16;
  const size_t kvBase = (size_t)bh * 2048 * 64;
  const int tB = z * ntile;

  const int srow = tid >> 3;                       // 0..63
  const int scol = (((tid & 7) * 16) ^ ((srow & 7) << 4)) >> 1;  // elem offset
  const u16* kSrcBase = Kh + kvBase + (size_t)srow * 64 + scol;
  const u16* vSrcBase = Vt + kvBase + (size_t)srow * 2048 + scol;

  s16x8 qf[2];
#pragma unroll
  for (int ks = 0; ks < 2; ++ks)
    qf[ks] = *(const s16x8*)(Qh + kvBase + (size_t)(q0 + lr) * 64 + ks * 32 + lh * 8);

  s16x8 onesf;
#pragma unroll
  for (int k = 0; k < 8; ++k) onesf[k] = (short)0x3F80;   // bf16 1.0

  f32x4 oacc[4];
  f32x4 aOnes = f32x4{0.f, 0.f, 0.f, 0.f};        // running row-sum
  float mrow = -1e30f;
#pragma unroll
  for (int d = 0; d < 4; ++d) oacc[d] = f32x4{0.f, 0.f, 0.f, 0.f};

  gl_lds16(kSrcBase + (size_t)tB * 4096, (char*)lsK[0] + wave * 1024);
  gl_lds16(vSrcBase + tB * 64,           (char*)lsV[0] + wave * 1024);

  for (int it = 0; it < ntile; ++it) {
    const int cur = it & 1;
    __syncthreads();

    s16x8 kb[2][4];
#pragma unroll
    for (int ks = 0; ks < 2; ++ks)
#pragma unroll
      for (int j = 0; j < 4; ++j) {
        int r = j * 16 + lr;
        kb[ks][j] = *(const s16x8*)((const char*)lsK[cur] + r * 128 +
                                    ((ks * 64 + lh * 16) ^ ((r & 7) << 4)));
      }

    if (it + 1 < ntile) {
      int t = tB + it + 1;
      gl_lds16(kSrcBase + (size_t)t * 4096, (char*)lsK[cur ^ 1] + wave * 1024);
      gl_lds16(vSrcBase + t * 64,           (char*)lsV[cur ^ 1] + wave * 1024);
    }

    f32x4 st[4];
#pragma unroll
    for (int j = 0; j < 4; ++j) st[j] = f32x4{0.f, 0.f, 0.f, 0.f};
    __builtin_amdgcn_s_setprio(1);
#pragma unroll
    for (int ks = 0; ks < 2; ++ks)
#pragma unroll
      for (int j = 0; j < 4; ++j) st[j] = mfma16(kb[ks][j], qf[ks], st[j]);
    __builtin_amdgcn_s_setprio(0);

    // in-lane max over 16 keys via v_max3 tree, then 2 shfls across lh
    float mx;
    {
      float t0 = max3f(st[0][0], st[0][1], st[0][2]);
      float t1 = max3f(st[0][3], st[1][0], st[1][1]);
      float t2 = max3f(st[1][2], st[1][3], st[2][0]);
      float t3 = max3f(st[2][1], st[2][2], st[2][3]);
      float t4 = max3f(st[3][0], st[3][1], st[3][2]);
      mx = fmaxf(max3f(t0, t1, t2), max3f(t3, t4, st[3][3]));
      mx = fmaxf(mx, __shfl_xor(mx, 16));
      mx = fmaxf(mx, __shfl_xor(mx, 32));
    }
    // defer-max: rescale only when some row grew > 2^11 (log2 domain)
    if (__any(mx > mrow + 11.f)) {
      float mn = fmaxf(mrow, mx);
      float al = exp2f(mrow - mn);
      mrow = mn;
#pragma unroll
      for (int q = 0; q < 4; ++q) aOnes[q] *= al;
#pragma unroll
      for (int d = 0; d < 4; ++d)
#pragma unroll
        for (int q = 0; q < 4; ++q) oacc[d][q] *= al;
    }

    // P = exp2(S - m) -> bf16 pairs -> LDS (row-sum via ones-MFMA below)
#pragma unroll
    for (int j = 0; j < 4; ++j) {
      float p0 = exp2f(st[j][0] - mrow);
      float p1 = exp2f(st[j][1] - mrow);
      float p2 = exp2f(st[j][2] - mrow);
      float p3 = exp2f(st[j][3] - mrow);
      u32x2 pk;
      pk.x = cvt_pk_bf16(p0, p1);
      pk.y = cvt_pk_bf16(p2, p3);
      *(u32x2*)((char*)lsP[wave] + lr * 128 + ((j * 32 + lh * 8) ^ ((lr & 7) << 4))) = pk;
    }

    // O^T += V^T P ; row-sum += ones^T P (same pa fragment, matrix pipe)
    __builtin_amdgcn_s_setprio(1);
#pragma unroll
    for (int ks = 0; ks < 2; ++ks) {
      s16x8 pa = *(const s16x8*)((const char*)lsP[wave] + lr * 128 +
                                 ((ks * 64 + lh * 16) ^ ((lr & 7) << 4)));
      aOnes = mfma16(onesf, pa, aOnes);
#pragma unroll
      for (int d = 0; d < 4; ++d) {
        int r = d * 16 + lr;
        s16x8 vb = *(const s16x8*)((const char*)lsV[cur] + r * 128 +
                                   ((ks * 64 + lh * 16) ^ ((r & 7) << 4)));
        oacc[d] = mfma16(vb, pa, oacc[d]);
      }
    }
    __builtin_amdgcn_s_setprio(0);
  }

  // epilogue: bf16 unnormalized partial O + (m, l)
  {
    int s = q0 + lr;
    size_t r = ((size_t)z * nbh + bh) * 2048 + s;
#pragma unroll
    for (int d = 0; d < 4; ++d) {
      u32x2 pk;
      pk.x = cvt_pk_bf16(oacc[d][0], oacc[d][1]);
      pk.y = cvt_pk_bf16(oacc[d][2], oacc[d][3]);
      *(u32x2*)(Opb + r * 64 + d * 16 + lh * 4) = pk;
    }
    if (lh == 0) { ml[r * 2] = mrow; ml[r * 2 + 1] = aOnes[0]; }
  }
}

// combine NZ KV-split bf16 partials -> ctx (bf16, [b][s][h*64+d] layout)
template <int NZ>
__global__ __launch_bounds__(256) void attn_combine(const u16* __restrict__ Opb,
                                                    const float* __restrict__ ml,
                                                    u16* __restrict__ ctx, int nbh) {
  size_t i = (size_t)blockIdx.x * 256 + threadIdx.x;   // nbh*2048*16 threads
  int d4 = (int)(i & 15);
  size_t rs = i >> 4;
  size_t zs = (size_t)nbh * 2048;
  float m[NZ], l[NZ];
  float mx = -1e30f;
#pragma unroll
  for (int p = 0; p < NZ; ++p) {
    m[p] = ml[(p * zs + rs) * 2];
    l[p] = ml[(p * zs + rs) * 2 + 1];
    mx = fmaxf(mx, m[p]);
  }
  float wsum = 0.f, a[NZ];
#pragma unroll
  for (int p = 0; p < NZ; ++p) { a[p] = exp2f(m[p] - mx); wsum += l[p] * a[p]; }
  float inv = 1.f / wsum;
  f32x4 o = f32x4{0.f, 0.f, 0.f, 0.f};
#pragma unroll
  for (int p = 0; p < NZ; ++p) {
    u16x4 op = *(const u16x4*)(Opb + (p * zs + rs) * 64 + d4 * 4);
#pragma unroll
    for (int k = 0; k < 4; ++k) o[k] += b2f(op[k]) * a[p];
  }
  int bh = (int)(rs >> 11), s = (int)(rs & 2047);
  int b = bh / 12, h = bh - b * 12;
  u16x4 r;
#pragma unroll
  for (int k = 0; k < 4; ++k) r[k] = f2b(o[k] * inv);
  *(u16x4*)(ctx + ((size_t)(b * 2048 + s)) * 768 + h * 64 + d4 * 4) = r;
}

// ---------------------------------------------------------------------------
// residual + LayerNorm over 768 (f32x4/u16x4 vectorized; lanes 0..191 hold 4
// cols). XBF=0: residual xin is fp32; XBF=1: residual xin is bf16.
// yin = sum of NP bf16 partials (split-K GEMM out).
// ---------------------------------------------------------------------------
template <int NP, int XBF>
__global__ __launch_bounds__(256) void resid_ln(const void* __restrict__ xin,
                                                const u16* __restrict__ yp,
                                                size_t pstride,
                                                const float* __restrict__ gamma,
                                                const float* __restrict__ beta,
                                                float* __restrict__ outf,
                                                u16* __restrict__ outb) {
  const int row = blockIdx.x, t = threadIdx.x;
  const size_t base4 = (size_t)row * 192;          // row offset in f32x4 units
  const bool act = t < 192;
  f32x4 v = f32x4{0.f, 0.f, 0.f, 0.f};
  float s = 0.f, s2 = 0.f;
  if (act) {
    if (XBF) {
      u16x4 xv = *(const u16x4*)((const u16*)xin + (size_t)row * 768 + t * 4);
#pragma unroll
      for (int k = 0; k < 4; ++k) v[k] = b2f(xv[k]);
    } else {
      v = ((const f32x4*)xin)[base4 + t];
    }
#pragma unroll
    for (int p = 0; p < NP; ++p) {
      u16x4 y = *(const u16x4*)(yp + p * pstride + (size_t)row * 768 + t * 4);
#pragma unroll
      for (int k = 0; k < 4; ++k) v[k] += b2f(y[k]);
    }
    s = (v[0] + v[1]) + (v[2] + v[3]);
    s2 = (v[0] * v[0] + v[1] * v[1]) + (v[2] * v[2] + v[3] * v[3]);
  }
#pragma unroll
  for (int off = 32; off > 0; off >>= 1) {
    s += __shfl_down(s, off, 64);
    s2 += __shfl_down(s2, off, 64);
  }
  __shared__ float red[8];
  int lane = t & 63, wave = t >> 6;
  if (lane == 0) { red[wave] = s; red[4 + wave] = s2; }
  __syncthreads();
  s = red[0] + red[1] + red[2] + red[3];
  s2 = red[4] + red[5] + red[6] + red[7];
  const float inv = 1.f / 768.f;
  float mu = s * inv;
  float var = fmaxf(s2 * inv - mu * mu, 0.f);
  float rs = rsqrtf(var + 1e-5f);
  if (act) {
    f32x4 g = ((const f32x4*)gamma)[t];
    f32x4 bb = ((const f32x4*)beta)[t];
    f32x4 o;
#pragma unroll
    for (int k = 0; k < 4; ++k) o[k] = (v[k] - mu) * rs * g[k] + bb[k];
    if (outf) ((f32x4*)outf)[base4 + t] = o;
    if (outb) {
      u16x4 ob;
#pragma unroll
      for (int k = 0; k < 4; ++k) ob[k] = f2b(o[k]);
      ((u16x4*)outb)[base4 + t] = ob;
    }
  }
}

// ---------------------------------------------------------------------------
extern "C" void kernel_launch(void* const* d_in, const int* in_sizes, int n_in,
                              void* d_out, int out_size, void* d_ws, size_t ws_size,
                              hipStream_t stream) {
  const float* x   = (const float*)d_in[0];
  const float* Wq  = (const float*)d_in[1];
  const float* bq  = (const float*)d_in[2];
  const float* Wk  = (const float*)d_in[3];
  const float* bk  = (const float*)d_in[4];
  const float* Wv  = (const float*)d_in[5];
  const float* bv  = (const float*)d_in[6];
  const float* Wo  = (const float*)d_in[7];
  const float* bo  = (const float*)d_in[8];
  const float* W1  = (const float*)d_in[9];
  const float* b1  = (const float*)d_in[10];
  const float* W2  = (const float*)d_in[11];
  const float* b2  = (const float*)d_in[12];
  const float* g1  = (const float*)d_in[13];
  const float* be1 = (const float*)d_in[14];
  const float* g2  = (const float*)d_in[15];
  const float* be2 = (const float*)d_in[16];
  float* out = (float*)d_out;

  const int M = in_sizes[0] / 768;   // 4096 tokens
  const int B = M / 2048;            // 2
  const int nbh = B * 12;

  char* ws = (char*)d_ws;
  size_t off = 0;
  auto alloc = [&](size_t bytes) -> void* {
    void* p = ws + off;
    off += (bytes + 255) & ~(size_t)255;
    return p;
  };
  u16*   Wqkv_t = (u16*)alloc((size_t)2304 * 768 * 2);
  u16*   Wo_t   = (u16*)alloc((size_t)768 * 768 * 2);
  u16*   W1_t   = (u16*)alloc((size_t)3072 * 768 * 2);
  u16*   W2_t   = (u16*)alloc((size_t)768 * 3072 * 2);
  float* bqkv   = (float*)alloc(2304 * 4);
  u16*   Xb     = (u16*)alloc((size_t)M * 768 * 2);      // reused as ctx
  u16*   Qh     = (u16*)alloc((size_t)M * 768 * 2);
  u16*   Kh     = (u16*)alloc((size_t)M * 768 * 2);
  u16*   Vt     = (u16*)alloc((size_t)M * 768 * 2);      // V^T, written by QKV GEMM

  size_t pstride = (size_t)M * 768;                      // elems per partial
  size_t fixedRest = pstride * 2 /*x1b*/ +
                     (size_t)M * 3072 * 2 /*hb*/ + 4096;
  const int ZSPLIT = 2;
  size_t opElems = (size_t)ZSPLIT * nbh * 2048 * 64;     // bf16
  size_t attnBytes = opElems * 2 + (size_t)ZSPLIT * nbh * 2048 * 2 * 4;
  size_t reg4 = attnBytes;
  if (reg4 < pstride * 2 * 4) reg4 = pstride * 2 * 4;    // 4 bf16 partials
  int FSPLIT;
  size_t regionBytes;
  if (off + reg4 + fixedRest <= ws_size) {
    FSPLIT = 4; regionBytes = reg4;
  } else {
    FSPLIT = 2;
    regionBytes = attnBytes > pstride * 2 * 2 ? attnBytes : pstride * 2 * 2;
  }
  float* region = (float*)alloc(regionBytes);
  u16*   Opb  = (u16*)region;
  float* ml   = (float*)((char*)region + opElems * 2);
  u16*   projPart = (u16*)region;              // alive after attn_combine
  u16*   ffnPart  = (u16*)region;              // alive after resid_ln<1st>
  u16*   x1b  = (u16*)alloc(pstride * 2);
  u16*   hb   = (u16*)alloc((size_t)M * 3072 * 2);
  u16*   ctx  = Xb;

  dim3 tb(32, 8);
  const int convBlocks = (M * 768) / 1024;
  prep<<<6912 + convBlocks + 9, tb, 0, stream>>>(
      Wq, Wk, Wv, Wo, W1, W2, bq, bk, bv, x,
      Wqkv_t, Wo_t, W1_t, W2_t, bqkv, Xb, convBlocks);

  // QKV projection; V written directly in transposed [bh][d][S] layout
  gemm_bt<2><<<dim3(2304 / 128, M / 128), 256, 0, stream>>>(
      Xb, Wqkv_t, bqkv, nullptr, Qh, Kh, Vt, M, 2304, 768, 768);

  attn<<<dim3(16, nbh, ZSPLIT), 512, 0, stream>>>(Qh, Kh, Vt, Opb, ml, nbh, 32 / ZSPLIT);
  attn_combine<2><<<nbh * 128, 256, 0, stream>>>(Opb, ml, ctx, nbh);

  // output projection, split-K x2 -> bf16 partials in region
  gemm_bt<0><<<dim3(768 / 128, M / 128, 2), 256, 0, stream>>>(
      ctx, Wo_t, bo, projPart, nullptr, nullptr, nullptr, M, 768, 768, 384);

  // LN1: residual = x (fp32); emit bf16 only (x1b feeds FFN1 and LN2)
  resid_ln<2, 0><<<M, 256, 0, stream>>>(x, projPart, pstride, g1, be1,
                                        nullptr, x1b);

  gemm_bt<1><<<dim3(3072 / 128, M / 128), 256, 0, stream>>>(
      x1b, W1_t, b1, hb, nullptr, nullptr, nullptr, M, 3072, 768, 768);

  if (FSPLIT == 4) {
    gemm_bt<0><<<dim3(768 / 128, M / 128, 4), 256, 0, stream>>>(
        hb, W2_t, b2, ffnPart, nullptr, nullptr, nullptr, M, 768, 3072, 768);
    resid_ln<4, 1><<<M, 256, 0, stream>>>(x1b, ffnPart, pstride, g2, be2,
                                          out, nullptr);
  } else {
    gemm_bt<0><<<dim3(768 / 128, M / 128, 2), 256, 0, stream>>>(
        hb, W2_t, b2, ffnPart, nullptr, nullptr, nullptr, M, 768, 3072, 1536);
    resid_ln<2, 1><<<M, 256, 0, stream>>>(x1b, ffnPart, pstride, g2, be2,
                                          out, nullptr);
  }
}